// Round 8
// baseline (483.280 us; speedup 1.0000x reference)
//
#include <hip/hip_runtime.h>

typedef unsigned short u16;
typedef unsigned int   u32;
typedef __bf16 bf16x8 __attribute__((ext_vector_type(8)));
typedef float  f32x4  __attribute__((ext_vector_type(4)));

__device__ __forceinline__ u16 f2bf(float f) {
    u32 u = __builtin_bit_cast(u32, f);
    u32 r = (u + 0x7FFFu + ((u >> 16) & 1u)) >> 16;
    return (u16)r;
}
__device__ __forceinline__ float bf2f(u16 v) {
    return __builtin_bit_cast(float, (u32)v << 16);
}
__device__ __forceinline__ float fexp2(float x) { return __builtin_amdgcn_exp2f(x); }
__device__ __forceinline__ float flog2(float x) { return __builtin_amdgcn_logf(x); }
__device__ __forceinline__ f32x4 mfma16(bf16x8 a, bf16x8 b, f32x4 c) {
    return __builtin_amdgcn_mfma_f32_16x16x32_bf16(a, b, c, 0, 0, 0);
}
__device__ __forceinline__ bf16x8 ld8(const u16* p) {
    return __builtin_bit_cast(bf16x8, *(const uint4*)p);
}
__device__ __forceinline__ void gload_lds16(const u16* g, u16* l) {
    __builtin_amdgcn_global_load_lds(
        (__attribute__((address_space(1))) void*)g,
        (__attribute__((address_space(3))) void*)l, 16, 0, 0);
}

// ---------------- fused prep: kvin + pos cvt + 3 weight transposes + convw ----------------
__global__ void prep_all(const float* __restrict__ x, const float* __restrict__ mem,
                         const float* __restrict__ cmem, const float* __restrict__ pos,
                         const float* __restrict__ Wq, const float* __restrict__ Wkv,
                         const float* __restrict__ Wout, const float* __restrict__ convw,
                         u16* __restrict__ kvin, u16* __restrict__ peb,
                         u16* __restrict__ WqT, u16* __restrict__ WkvT,
                         u16* __restrict__ WoutT, u16* __restrict__ convWT) {
    __shared__ float tile[32][33];
    const int bid = blockIdx.x, tid = threadIdx.x;
    if (bid < 9216) {
        const size_t i = ((size_t)bid * 256 + tid) * 4;
        const int row = (int)(i >> 10), col = (int)(i & 1023);
        const int b = row / 2304, j = row - b * 2304;
        const float* src;
        if (j < 256)       src = cmem + ((size_t)(b * 256  + j) << 10);
        else if (j < 1280) src = mem  + ((size_t)(b * 1024 + j - 256) << 10);
        else               src = x    + ((size_t)(b * 1024 + j - 1280) << 10);
        float4 v = *(const float4*)(src + col);
        uint2 o;
        o.x = (u32)f2bf(v.x) | ((u32)f2bf(v.y) << 16);
        o.y = (u32)f2bf(v.z) | ((u32)f2bf(v.w) << 16);
        *(uint2*)(kvin + i) = o;
    } else if (bid < 11520) {
        const int i = ((bid - 9216) * 256 + tid) * 4;
        float4 v = *(const float4*)(pos + i);
        uint2 o;
        o.x = (u32)f2bf(v.x) | ((u32)f2bf(v.y) << 16);
        o.y = (u32)f2bf(v.z) | ((u32)f2bf(v.w) << 16);
        *(uint2*)(peb + i) = o;
    } else if (bid < 15616) {
        const float* in; u16* out; int K, N, bx, by;
        if (bid < 12544)      { in = Wq;   out = WqT;   K = 1024; N = 1024;
                                const int t = bid - 11520; bx = t & 31, by = t >> 5; }
        else if (bid < 14592) { in = Wkv;  out = WkvT;  K = 1024; N = 2048;
                                const int t = bid - 12544; bx = t & 63, by = t >> 6; }
        else                  { in = Wout; out = WoutT; K = 1024; N = 1024;
                                const int t = bid - 14592; bx = t & 31, by = t >> 5; }
        const int tx = tid & 31, ty = tid >> 5;
        #pragma unroll
        for (int i = 0; i < 32; i += 8)
            tile[ty + i][tx] = in[(size_t)(by * 32 + ty + i) * N + bx * 32 + tx];
        __syncthreads();
        #pragma unroll
        for (int i = 0; i < 32; i += 8)
            out[(size_t)(bx * 32 + ty + i) * K + by * 32 + tx] = f2bf(tile[tx][ty + i]);
    } else {
        const int o = bid - 15616;
        const float* src = convw + (size_t)o * 4096;
        u16* dst = convWT + (size_t)o * 4096;
        #pragma unroll
        for (int it = 0; it < 4; ++it) {
            const int d = it * 256 + tid;
            float4 v = *(const float4*)(src + d * 4);
            dst[d]        = f2bf(v.x);
            dst[1024 + d] = f2bf(v.y);
            dst[2048 + d] = f2bf(v.z);
            dst[3072 + d] = f2bf(v.w);
        }
    }
}

// ---------------- bf16 GEMM (m97-style global_load_lds staging) ----------------
// OUTMODE: 1 = f32 + bias, 2 = bf16, 4 = KV fused (K-half -> Cb, V-half -> Vt via LDS transpose)
template<int OUTMODE, int BM, int BN>
__global__ __launch_bounds__(256)
void gemm_bt(const u16* __restrict__ A, const u16* __restrict__ BT,
             float* __restrict__ Cf, u16* __restrict__ Cb,
             const float* __restrict__ bias,
             int N, int K, int rowblk, int rowstride, int rowoff,
             u16* __restrict__ Vt) {
    constexpr int FM = BM / 32, FN = BN / 32;
    constexpr int IA = BM / 64, IB = BN / 64;
    constexpr int STG = (BM + BN) * 32;
    constexpr int SHSZ = (OUTMODE == 4) ? (STG > 64 * 136 ? STG : 64 * 136) : STG;
    __shared__ __align__(16) u16 sh[SHSZ];
    u16* As = sh;
    u16* Bs = sh + BM * 32;
    const int tid = threadIdx.x;
    const int wv = tid >> 6, lane = tid & 63;
    const int fr = lane & 15, fg = lane >> 4;
    const int m0 = blockIdx.y * BM, n0 = blockIdx.x * BN;
    const int wr = (wv >> 1) * (BM / 2), wc = (wv & 1) * (BN / 2);

    size_t aoff[IA], boff[IB];
    #pragma unroll
    for (int i = 0; i < IA; ++i) {
        const int ag = m0 + wv * (BM / 4) + i * 16 + (lane >> 2);
        const size_t arow = (size_t)(ag / rowblk) * rowstride + (ag % rowblk) + rowoff;
        aoff[i] = arow * K + (lane & 3) * 8;
    }
    #pragma unroll
    for (int i = 0; i < IB; ++i) {
        const int bg = n0 + wv * (BN / 4) + i * 16 + (lane >> 2);
        boff[i] = (size_t)bg * K + (lane & 3) * 8;
    }

    f32x4 acc[FM][FN] = {};
    const int nk = K / 32;
    for (int kt = 0; kt < nk; ++kt) {
        __syncthreads();
        #pragma unroll
        for (int i = 0; i < IA; ++i)
            gload_lds16(A + aoff[i] + kt * 32, As + wv * (BM * 8) + i * 512);
        #pragma unroll
        for (int i = 0; i < IB; ++i)
            gload_lds16(BT + boff[i] + kt * 32, Bs + wv * (BN * 8) + i * 512);
        __syncthreads();
        bf16x8 af[FM], bfv[FN];
        #pragma unroll
        for (int i = 0; i < FM; ++i)
            af[i] = ld8(As + (wr + i * 16 + fr) * 32 + fg * 8);
        #pragma unroll
        for (int i = 0; i < FN; ++i)
            bfv[i] = ld8(Bs + (wc + i * 16 + fr) * 32 + fg * 8);
        #pragma unroll
        for (int mi = 0; mi < FM; ++mi)
            #pragma unroll
            for (int ni = 0; ni < FN; ++ni)
                acc[mi][ni] = mfma16(af[mi], bfv[ni], acc[mi][ni]);
    }
    if (OUTMODE == 4 && n0 >= 1024) {
        const int bb = m0 / 2304;
        const int j0 = m0 - bb * 2304;
        const int c0 = n0 - 1024;
        #pragma unroll
        for (int p = 0; p < 2; ++p) {
            __syncthreads();
            if ((wv & 1) == p) {
                #pragma unroll
                for (int mi = 0; mi < FM; ++mi)
                    #pragma unroll
                    for (int ni = 0; ni < FN; ++ni)
                        #pragma unroll
                        for (int r = 0; r < 4; ++r)
                            sh[(ni * 16 + fr) * 136 + wr + mi * 16 + fg * 4 + r]
                                = f2bf(acc[mi][ni][r]);
            }
            __syncthreads();
            #pragma unroll
            for (int it = 0; it < 2; ++it) {
                const int idx = it * 256 + tid;
                const int d = idx >> 3, jo = (idx & 7) * 16;
                *(uint4*)(Vt + ((size_t)(bb * 1024 + c0 + p * 64 + d)) * 2304 + j0 + jo)
                    = *(const uint4*)(sh + d * 136 + jo);
            }
        }
        return;
    }
    #pragma unroll
    for (int mi = 0; mi < FM; ++mi) {
        #pragma unroll
        for (int ni = 0; ni < FN; ++ni) {
            const int col = n0 + wc + ni * 16 + fr;
            const float bv = (OUTMODE == 1) ? bias[col] : 0.0f;
            #pragma unroll
            for (int r = 0; r < 4; ++r) {
                const int row = m0 + wr + mi * 16 + fg * 4 + r;
                const float v = acc[mi][ni][r] + bv;
                if (OUTMODE == 1) Cf[(size_t)row * N + col] = v;
                else              Cb[(size_t)row * N + col] = f2bf(v);
            }
        }
    }
}

// ---------------- fused attention: T14 reg-staged pipeline, raw barriers ----------------
// Per chunk: vmcnt(0) -> ds_write staged regs -> lgkmcnt(0)+s_barrier ->
//            issue next-chunk loads (stay in flight ACROSS the bottom barrier) ->
//            QK+PE MFMA -> softmax -> PV(LDS) -> lgkmcnt(0)+s_barrier.
__global__ __launch_bounds__(256, 2)
void attn_fused6(const u16* __restrict__ Qb, const u16* __restrict__ KVb,
                 const u16* __restrict__ Vtb, const u16* __restrict__ peb,
                 u16* __restrict__ O01, float* __restrict__ lsep,
                 u16* __restrict__ O2) {
    // T1: bid&7 = XCD; each XCD owns 12 consecutive (b,h,sp) groups x 16 qt.
    const int bid = blockIdx.x;
    const int xcd = bid & 7, ii = bid >> 3;
    const int G = xcd * 12 + (ii >> 4), qt = ii & 15;
    const int b = G / 24, rem = G - b * 24;
    const int h = rem / 3, sp = rem - (rem / 3) * 3;

    const int tid = threadIdx.x, w = tid >> 6, lane = tid & 63;
    const int fr = lane & 15, fg = lane >> 4;
    const int q0 = qt * 64, q0w = q0 + w * 16;
    const int n64 = min(2304, q0 + 1344) >> 6;
    const int base = n64 / 3, rm = n64 - base * 3;
    const int cbeg = sp * base + min(sp, rm);
    const int cnt = base + (sp < rm ? 1 : 0);
    const int kbeg = cbeg << 6, kend = (cbeg + cnt) << 6;

    __shared__ __align__(16) u16 Ks[64 * 128];      // row-swizzled
    __shared__ __align__(16) u16 Vs[128 * 64];      // row-swizzled
    __shared__ __align__(16) u16 PEs[2][64 * 128];  // sliding 128-row PE band ring
    __shared__ __align__(16) u16 sc[4][16][104];    // per-wave ppe/p scratch

    const u16* kvbase = KVb + (size_t)b * 2304 * 2048 + h * 128;
    const u16* vtbase = Vtb + (size_t)(b * 8 + h) * 128 * 2304;
    const u16* pebase = peb + (size_t)h * 2304 * 128;
    const float scale2 = 0.088388347648318447f * 1.4426950408889634f;

    bf16x8 qf[4];
    {
        const u16* qp = Qb + (size_t)(b * 1024 + q0w + fr) * 1024 + h * 128 + fg * 8;
        #pragma unroll
        for (int dc = 0; dc < 4; ++dc) qf[dc] = ld8(qp + dc * 32);
    }

    // per-lane staging geometry (linear global loads, swizzled LDS writes)
    const int kr0 = w * 16 + (lane >> 4);   // +i*4
    const int vr0 = w * 32 + (lane >> 3);   // +i*8
    const int kc = (lane & 15) * 8;         // K/PE col (u16)
    const int vc = (lane & 7) * 8;          // V col (u16)

    // prologue: issue loads for chunk kbeg (K, V, PE-lo, PE-hi)
    uint4 vK[4], vV[4], vPhi[4], vPlo[4];
    #pragma unroll
    for (int i = 0; i < 4; ++i) {
        const int kr = kr0 + i * 4;
        vK[i] = *(const uint4*)(kvbase + (size_t)(kbeg + kr) * 2048 + kc);
        const int vr = vr0 + i * 8;
        vV[i] = *(const uint4*)(vtbase + (size_t)vr * 2304 + kbeg + vc);
        int jlo = kbeg - q0 + 960 + kr;  if (jlo >= 2304) jlo = 0;
        int jhi = kbeg - q0 + 1024 + kr; if (jhi >= 2304) jhi = 0;
        vPlo[i] = *(const uint4*)(pebase + (size_t)jlo * 128 + kc);
        vPhi[i] = *(const uint4*)(pebase + (size_t)jhi * 128 + kc);
    }

    f32x4 o[8] = {};
    float mrow[4] = {-1e30f, -1e30f, -1e30f, -1e30f};
    float lrow[4] = {};

    for (int k0 = kbeg; k0 < kend; k0 += 64) {
        const int cc = (k0 - q0) >> 6;
        // staged loads have had a full chunk of compute to land
        asm volatile("s_waitcnt vmcnt(0)" ::: "memory");
        #pragma unroll
        for (int i = 0; i < 4; ++i) {
            const int kr = kr0 + i * 4;
            *(uint4*)(Ks + kr * 128 + (kc ^ ((kr & 7) * 8))) = vK[i];
            const int vr = vr0 + i * 8;
            *(uint4*)(Vs + vr * 64 + (vc ^ ((vr & 7) * 8))) = vV[i];
        }
        {
            u16* pslot = &PEs[(cc + 16) & 1][0];
            #pragma unroll
            for (int i = 0; i < 4; ++i) {
                const int pr = kr0 + i * 4;
                *(uint4*)(pslot + pr * 128 + (kc ^ ((pr & 7) * 8))) = vPhi[i];
            }
        }
        if (k0 == kbeg) {
            u16* pslot = &PEs[(cc + 15) & 1][0];
            #pragma unroll
            for (int i = 0; i < 4; ++i) {
                const int pr = kr0 + i * 4;
                *(uint4*)(pslot + pr * 128 + (kc ^ ((pr & 7) * 8))) = vPlo[i];
            }
        }
        asm volatile("s_waitcnt lgkmcnt(0)" ::: "memory");
        __builtin_amdgcn_s_barrier();
        __builtin_amdgcn_sched_barrier(0);

        // issue next chunk's loads NOW; they stay in flight across the bottom barrier
        if (k0 + 64 < kend) {
            #pragma unroll
            for (int i = 0; i < 4; ++i) {
                const int kr = kr0 + i * 4;
                vK[i] = *(const uint4*)(kvbase + (size_t)(k0 + 64 + kr) * 2048 + kc);
                const int vr = vr0 + i * 8;
                vV[i] = *(const uint4*)(vtbase + (size_t)vr * 2304 + (k0 + 64) + vc);
                int jn = k0 - q0 + 1088 + kr; if (jn >= 2304) jn = 0;
                vPhi[i] = *(const uint4*)(pebase + (size_t)jn * 128 + kc);
            }
        }

        // ---- S = Q K^T + PE band, all LDS-fed ----
        __builtin_amdgcn_s_setprio(1);
        f32x4 s[4] = {};
        #pragma unroll
        for (int kb = 0; kb < 4; ++kb) {
            const int row = kb * 16 + fr;
            #pragma unroll
            for (int dc = 0; dc < 4; ++dc) {
                bf16x8 kf = ld8(Ks + row * 128 + ((dc * 32 + fg * 8) ^ ((row & 7) << 3)));
                s[kb] = mfma16(qf[dc], kf, s[kb]);
            }
        }
        const u16* pl = &PEs[(cc + 15) & 1][0];
        const u16* pu = &PEs[(cc + 16) & 1][0];
        f32x4 pp[5] = {};
        #pragma unroll
        for (int jb = 0; jb < 5; ++jb) {
            const int lstart = 48 - 16 * w + 16 * jb;
            const u16* pbase = (lstart < 64) ? (pl + lstart * 128) : (pu + (lstart - 64) * 128);
            #pragma unroll
            for (int dc = 0; dc < 4; ++dc) {
                bf16x8 pf = ld8(pbase + fr * 128 + ((dc * 32 + fg * 8) ^ ((fr & 7) << 3)));
                pp[jb] = mfma16(qf[dc], pf, pp[jb]);
            }
        }
        __builtin_amdgcn_s_setprio(0);
        #pragma unroll
        for (int jb = 0; jb < 5; ++jb)
            #pragma unroll
            for (int r = 0; r < 4; ++r)
                sc[w][fg * 4 + r][jb * 16 + fr] = f2bf(pp[jb][r]);
        asm volatile("s_waitcnt lgkmcnt(0)" ::: "memory");

        // ---- combine + mask + online softmax (exp2 domain) ----
        const bool need_mask = (k0 + 63) > (q0w + 1280);
        float pv[4][4], mx[4];
        #pragma unroll
        for (int r = 0; r < 4; ++r) mx[r] = mrow[r];
        #pragma unroll
        for (int kb = 0; kb < 4; ++kb) {
            #pragma unroll
            for (int r = 0; r < 4; ++r) {
                const int qq = fg * 4 + r;
                float v = (s[kb][r] + bf2f(sc[w][qq][kb * 16 + fr + 15 - qq])) * scale2;
                if (need_mask && (k0 + kb * 16 + fr) > (q0w + qq + 1280)) v = -1e30f;
                pv[kb][r] = v;
                mx[r] = fmaxf(mx[r], v);
            }
        }
        #pragma unroll
        for (int r = 0; r < 4; ++r) {
            mx[r] = fmaxf(mx[r], __shfl_xor(mx[r], 1));
            mx[r] = fmaxf(mx[r], __shfl_xor(mx[r], 2));
            mx[r] = fmaxf(mx[r], __shfl_xor(mx[r], 4));
            mx[r] = fmaxf(mx[r], __shfl_xor(mx[r], 8));
        }
        // T13 defer-rescale
        const float growth = fmaxf(fmaxf(mx[0] - mrow[0], mx[1] - mrow[1]),
                                   fmaxf(mx[2] - mrow[2], mx[3] - mrow[3]));
        if (!__all(growth <= 8.0f)) {
            #pragma unroll
            for (int r = 0; r < 4; ++r) {
                const float a = fexp2(mrow[r] - mx[r]);
                mrow[r] = mx[r];
                lrow[r] *= a;
                #pragma unroll
                for (int db = 0; db < 8; ++db) o[db][r] *= a;
            }
        }
        float rsum[4] = {};
        #pragma unroll
        for (int kb = 0; kb < 4; ++kb)
            #pragma unroll
            for (int r = 0; r < 4; ++r) {
                const float p = fexp2(pv[kb][r] - mrow[r]);
                pv[kb][r] = p;
                rsum[r] += p;
            }
        #pragma unroll
        for (int r = 0; r < 4; ++r) {
            rsum[r] += __shfl_xor(rsum[r], 1);
            rsum[r] += __shfl_xor(rsum[r], 2);
            rsum[r] += __shfl_xor(rsum[r], 4);
            rsum[r] += __shfl_xor(rsum[r], 8);
            lrow[r] += rsum[r];
        }
        // ---- P to scratch (bf16, per-wave region) ----
        #pragma unroll
        for (int kb = 0; kb < 4; ++kb)
            #pragma unroll
            for (int r = 0; r < 4; ++r)
                sc[w][fg * 4 + r][kb * 16 + fr] = f2bf(pv[kb][r]);
        asm volatile("s_waitcnt lgkmcnt(0)" ::: "memory");
        // ---- O += P V (V from LDS) ----
        __builtin_amdgcn_s_setprio(1);
        #pragma unroll
        for (int ks = 0; ks < 2; ++ks) {
            bf16x8 pa = __builtin_bit_cast(bf16x8, *(const uint4*)(&sc[w][fr][ks * 32 + fg * 8]));
            #pragma unroll
            for (int db = 0; db < 8; ++db) {
                const int d = db * 16 + fr;
                bf16x8 vf = ld8(Vs + d * 64 + ((ks * 32 + fg * 8) ^ ((d & 7) << 3)));
                o[db] = mfma16(pa, vf, o[db]);
            }
        }
        __builtin_amdgcn_s_setprio(0);
        // LDS reads done (lgkm only) -> safe for next iteration's ds_writes.
        // Raw barrier: next-chunk global loads stay in flight.
        asm volatile("s_waitcnt lgkmcnt(0)" ::: "memory");
        __builtin_amdgcn_s_barrier();
    }
    // ---- epilogue: normalized partial + lse (log2 domain) ----
    float inv[4], lse[4];
    #pragma unroll
    for (int r = 0; r < 4; ++r) {
        inv[r] = 1.0f / lrow[r];
        lse[r] = mrow[r] + flog2(lrow[r]);
    }
    u16* dst = (sp == 2) ? O2 : (O01 + (size_t)sp * 4194304);
    #pragma unroll
    for (int db = 0; db < 8; ++db)
        #pragma unroll
        for (int r = 0; r < 4; ++r)
            dst[(size_t)(b * 1024 + q0w + fg * 4 + r) * 1024 + h * 128 + db * 16 + fr]
                = f2bf(o[db][r] * inv[r]);
    if (fr == 0) {
        #pragma unroll
        for (int r = 0; r < 4; ++r)
            lsep[sp * 32768 + (b * 8 + h) * 1024 + q0w + fg * 4 + r] = lse[r];
    }
}

// combine 3 flash partials (lse in log2 domain)
__global__ void attn_combine(const u16* __restrict__ O01, const float* __restrict__ lsep,
                             u16* __restrict__ O2) {
    const int i = (blockIdx.x * 256 + threadIdx.x) * 8;
    const int row = i >> 10;
    const int b = row >> 10, q = row & 1023;
    const int h = (i & 1023) >> 7;
    const int li = (b * 8 + h) * 1024 + q;
    const float l0 = lsep[li], l1 = lsep[li + 32768], l2 = lsep[li + 65536];
    const float M = fmaxf(l0, fmaxf(l1, l2));
    const float w0 = fexp2(l0 - M), w1 = fexp2(l1 - M), w2 = fexp2(l2 - M);
    const float inv = 1.0f / (w0 + w1 + w2);
    uint4 a = *(const uint4*)(O01 + i);
    uint4 c = *(const uint4*)(O01 + 4194304 + i);
    uint4 e = *(const uint4*)(O2 + i);
    const u16* ap = (const u16*)&a;
    const u16* cp = (const u16*)&c;
    const u16* ep = (const u16*)&e;
    u16 ov[8];
    #pragma unroll
    for (int j = 0; j < 8; ++j)
        ov[j] = f2bf((w0 * bf2f(ap[j]) + w1 * bf2f(cp[j]) + w2 * bf2f(ep[j])) * inv);
    *(uint4*)(O2 + i) = *(const uint4*)ov;
}

// ---------------- launch ----------------

extern "C" void kernel_launch(void* const* d_in, const int* in_sizes, int n_in,
                              void* d_out, int out_size, void* d_ws, size_t ws_size,
                              hipStream_t stream) {
    const float* x     = (const float*)d_in[0];
    const float* mem   = (const float*)d_in[1];
    const float* cmem  = (const float*)d_in[2];
    const float* pos   = (const float*)d_in[3];
    const float* Wq    = (const float*)d_in[5];
    const float* Wkv   = (const float*)d_in[6];
    const float* Wout  = (const float*)d_in[7];
    const float* bout  = (const float*)d_in[8];
    const float* convw = (const float*)d_in[9];
    const float* convb = (const float*)d_in[10];
    float* out = (float*)d_out;

    u16* ws = (u16*)d_ws;
    size_t off = 0;
    u16* kvin   = ws + off; off += (size_t)9216 * 1024;   // also reused as O-partials
    u16* WqT    = ws + off; off += (size_t)1024 * 1024;
    u16* WkvT   = ws + off; off += (size_t)2048 * 1024;
    u16* WoutT  = ws + off; off += (size_t)1024 * 1024;
    u16* convWT = ws + off; off += (size_t)1024 * 4096;
    u16* peb    = ws + off; off += (size_t)8 * 2304 * 128;
    u16* Qb     = ws + off; off += (size_t)4096 * 1024;
    u16* KVb    = ws + off; off += (size_t)9216 * 2048;
    u16* Vtb    = ws + off; off += (size_t)4 * 8 * 128 * 2304;
    u16* attn   = ws + off; off += (size_t)4096 * 1024;

    u16* O01 = kvin;                             // splits 0,1: 2 x 4194304 u16
    float* lsep = (float*)(kvin + 8388608);      // 3 x 32768 f32

    prep_all<<<16640, 256, 0, stream>>>(x, mem, cmem, pos, Wq, Wkv, Wout, convw,
                                        kvin, peb, WqT, WkvT, WoutT, convWT);

    // Q = x @ Wq  (rows remapped into kvin)
    gemm_bt<2, 128, 128><<<dim3(8, 32), 256, 0, stream>>>(
        kvin, WqT, nullptr, Qb, nullptr, 1024, 1024, 1024, 2304, 1280, nullptr);
    // KV = kv_input @ Wkv ; V-half written transposed (via LDS) into Vtb
    gemm_bt<4, 128, 128><<<dim3(16, 72), 256, 0, stream>>>(
        kvin, WkvT, nullptr, KVb, nullptr, 2048, 1024, 9216, 0, 0, Vtb);

    // new_cmem (conv) BEFORE attention clobbers kvin
    gemm_bt<1, 64, 64><<<dim3(16, 16), 256, 0, stream>>>(
        kvin, convWT, out + 8388608, nullptr, convb, 1024, 4096, 256, 576, 64, nullptr);
    // new_mem = x
    hipMemcpyAsync(out + 4194304, x, (size_t)4 * 1024 * 1024 * 4,
                   hipMemcpyDeviceToDevice, stream);

    attn_fused6<<<dim3(1536), 256, 0, stream>>>(Qb, KVb, Vtb, peb, O01, lsep, attn);
    attn_combine<<<2048, 256, 0, stream>>>(O01, lsep, attn);

    // logits = attn_out @ Wout + b_out
    gemm_bt<1, 128, 128><<<dim3(8, 32), 256, 0, stream>>>(
        attn, WoutT, out, nullptr, bout, 1024, 1024, 4096, 0, 0, nullptr);
    // aux_loss = 0
    hipMemsetAsync(out + 9437184, 0, 4, stream);
}

// Round 9
// 339.322 us; speedup vs baseline: 1.4243x; 1.4243x over previous
//
#include <hip/hip_runtime.h>

typedef unsigned short u16;
typedef unsigned int   u32;
typedef __bf16 bf16x8 __attribute__((ext_vector_type(8)));
typedef float  f32x4  __attribute__((ext_vector_type(4)));

__device__ __forceinline__ u16 f2bf(float f) {
    u32 u = __builtin_bit_cast(u32, f);
    u32 r = (u + 0x7FFFu + ((u >> 16) & 1u)) >> 16;
    return (u16)r;
}
__device__ __forceinline__ float bf2f(u16 v) {
    return __builtin_bit_cast(float, (u32)v << 16);
}
__device__ __forceinline__ float fexp2(float x) { return __builtin_amdgcn_exp2f(x); }
__device__ __forceinline__ float flog2(float x) { return __builtin_amdgcn_logf(x); }
__device__ __forceinline__ f32x4 mfma16(bf16x8 a, bf16x8 b, f32x4 c) {
    return __builtin_amdgcn_mfma_f32_16x16x32_bf16(a, b, c, 0, 0, 0);
}
__device__ __forceinline__ bf16x8 ld8(const u16* p) {
    return __builtin_bit_cast(bf16x8, *(const uint4*)p);
}
__device__ __forceinline__ void gload_lds16(const u16* g, u16* l) {
    __builtin_amdgcn_global_load_lds(
        (__attribute__((address_space(1))) void*)g,
        (__attribute__((address_space(3))) void*)l, 16, 0, 0);
}

// ---------------- fused prep: kvin + pos cvt + 3 weight transposes + convw ----------------
__global__ void prep_all(const float* __restrict__ x, const float* __restrict__ mem,
                         const float* __restrict__ cmem, const float* __restrict__ pos,
                         const float* __restrict__ Wq, const float* __restrict__ Wkv,
                         const float* __restrict__ Wout, const float* __restrict__ convw,
                         u16* __restrict__ kvin, u16* __restrict__ peb,
                         u16* __restrict__ WqT, u16* __restrict__ WkvT,
                         u16* __restrict__ WoutT, u16* __restrict__ convWT) {
    __shared__ float tile[32][33];
    const int bid = blockIdx.x, tid = threadIdx.x;
    if (bid < 9216) {
        const size_t i = ((size_t)bid * 256 + tid) * 4;
        const int row = (int)(i >> 10), col = (int)(i & 1023);
        const int b = row / 2304, j = row - b * 2304;
        const float* src;
        if (j < 256)       src = cmem + ((size_t)(b * 256  + j) << 10);
        else if (j < 1280) src = mem  + ((size_t)(b * 1024 + j - 256) << 10);
        else               src = x    + ((size_t)(b * 1024 + j - 1280) << 10);
        float4 v = *(const float4*)(src + col);
        uint2 o;
        o.x = (u32)f2bf(v.x) | ((u32)f2bf(v.y) << 16);
        o.y = (u32)f2bf(v.z) | ((u32)f2bf(v.w) << 16);
        *(uint2*)(kvin + i) = o;
    } else if (bid < 11520) {
        const int i = ((bid - 9216) * 256 + tid) * 4;
        float4 v = *(const float4*)(pos + i);
        uint2 o;
        o.x = (u32)f2bf(v.x) | ((u32)f2bf(v.y) << 16);
        o.y = (u32)f2bf(v.z) | ((u32)f2bf(v.w) << 16);
        *(uint2*)(peb + i) = o;
    } else if (bid < 15616) {
        const float* in; u16* out; int K, N, bx, by;
        if (bid < 12544)      { in = Wq;   out = WqT;   K = 1024; N = 1024;
                                const int t = bid - 11520; bx = t & 31, by = t >> 5; }
        else if (bid < 14592) { in = Wkv;  out = WkvT;  K = 1024; N = 2048;
                                const int t = bid - 12544; bx = t & 63, by = t >> 6; }
        else                  { in = Wout; out = WoutT; K = 1024; N = 1024;
                                const int t = bid - 14592; bx = t & 31, by = t >> 5; }
        const int tx = tid & 31, ty = tid >> 5;
        #pragma unroll
        for (int i = 0; i < 32; i += 8)
            tile[ty + i][tx] = in[(size_t)(by * 32 + ty + i) * N + bx * 32 + tx];
        __syncthreads();
        #pragma unroll
        for (int i = 0; i < 32; i += 8)
            out[(size_t)(bx * 32 + ty + i) * K + by * 32 + tx] = f2bf(tile[tx][ty + i]);
    } else {
        const int o = bid - 15616;
        const float* src = convw + (size_t)o * 4096;
        u16* dst = convWT + (size_t)o * 4096;
        #pragma unroll
        for (int it = 0; it < 4; ++it) {
            const int d = it * 256 + tid;
            float4 v = *(const float4*)(src + d * 4);
            dst[d]        = f2bf(v.x);
            dst[1024 + d] = f2bf(v.y);
            dst[2048 + d] = f2bf(v.z);
            dst[3072 + d] = f2bf(v.w);
        }
    }
}

// ---------------- bf16 GEMM (m97-style global_load_lds staging) ----------------
// OUTMODE: 1 = f32 + bias, 2 = bf16, 4 = KV fused (K-half -> Cb, V-half -> Vt via LDS transpose)
template<int OUTMODE, int BM, int BN>
__global__ __launch_bounds__(256)
void gemm_bt(const u16* __restrict__ A, const u16* __restrict__ BT,
             float* __restrict__ Cf, u16* __restrict__ Cb,
             const float* __restrict__ bias,
             int N, int K, int rowblk, int rowstride, int rowoff,
             u16* __restrict__ Vt) {
    constexpr int FM = BM / 32, FN = BN / 32;
    constexpr int IA = BM / 64, IB = BN / 64;
    constexpr int STG = (BM + BN) * 32;
    constexpr int SHSZ = (OUTMODE == 4) ? (STG > 64 * 136 ? STG : 64 * 136) : STG;
    __shared__ __align__(16) u16 sh[SHSZ];
    u16* As = sh;
    u16* Bs = sh + BM * 32;
    const int tid = threadIdx.x;
    const int wv = tid >> 6, lane = tid & 63;
    const int fr = lane & 15, fg = lane >> 4;
    const int m0 = blockIdx.y * BM, n0 = blockIdx.x * BN;
    const int wr = (wv >> 1) * (BM / 2), wc = (wv & 1) * (BN / 2);

    size_t aoff[IA], boff[IB];
    #pragma unroll
    for (int i = 0; i < IA; ++i) {
        const int ag = m0 + wv * (BM / 4) + i * 16 + (lane >> 2);
        const size_t arow = (size_t)(ag / rowblk) * rowstride + (ag % rowblk) + rowoff;
        aoff[i] = arow * K + (lane & 3) * 8;
    }
    #pragma unroll
    for (int i = 0; i < IB; ++i) {
        const int bg = n0 + wv * (BN / 4) + i * 16 + (lane >> 2);
        boff[i] = (size_t)bg * K + (lane & 3) * 8;
    }

    f32x4 acc[FM][FN] = {};
    const int nk = K / 32;
    for (int kt = 0; kt < nk; ++kt) {
        __syncthreads();
        #pragma unroll
        for (int i = 0; i < IA; ++i)
            gload_lds16(A + aoff[i] + kt * 32, As + wv * (BM * 8) + i * 512);
        #pragma unroll
        for (int i = 0; i < IB; ++i)
            gload_lds16(BT + boff[i] + kt * 32, Bs + wv * (BN * 8) + i * 512);
        __syncthreads();
        bf16x8 af[FM], bfv[FN];
        #pragma unroll
        for (int i = 0; i < FM; ++i)
            af[i] = ld8(As + (wr + i * 16 + fr) * 32 + fg * 8);
        #pragma unroll
        for (int i = 0; i < FN; ++i)
            bfv[i] = ld8(Bs + (wc + i * 16 + fr) * 32 + fg * 8);
        #pragma unroll
        for (int mi = 0; mi < FM; ++mi)
            #pragma unroll
            for (int ni = 0; ni < FN; ++ni)
                acc[mi][ni] = mfma16(af[mi], bfv[ni], acc[mi][ni]);
    }
    if (OUTMODE == 4 && n0 >= 1024) {
        const int bb = m0 / 2304;
        const int j0 = m0 - bb * 2304;
        const int c0 = n0 - 1024;
        #pragma unroll
        for (int p = 0; p < 2; ++p) {
            __syncthreads();
            if ((wv & 1) == p) {
                #pragma unroll
                for (int mi = 0; mi < FM; ++mi)
                    #pragma unroll
                    for (int ni = 0; ni < FN; ++ni)
                        #pragma unroll
                        for (int r = 0; r < 4; ++r)
                            sh[(ni * 16 + fr) * 136 + wr + mi * 16 + fg * 4 + r]
                                = f2bf(acc[mi][ni][r]);
            }
            __syncthreads();
            #pragma unroll
            for (int it = 0; it < 2; ++it) {
                const int idx = it * 256 + tid;
                const int d = idx >> 3, jo = (idx & 7) * 16;
                *(uint4*)(Vt + ((size_t)(bb * 1024 + c0 + p * 64 + d)) * 2304 + j0 + jo)
                    = *(const uint4*)(sh + d * 136 + jo);
            }
        }
        return;
    }
    #pragma unroll
    for (int mi = 0; mi < FM; ++mi) {
        #pragma unroll
        for (int ni = 0; ni < FN; ++ni) {
            const int col = n0 + wc + ni * 16 + fr;
            const float bv = (OUTMODE == 1) ? bias[col] : 0.0f;
            #pragma unroll
            for (int r = 0; r < 4; ++r) {
                const int row = m0 + wr + mi * 16 + fg * 4 + r;
                const float v = acc[mi][ni][r] + bv;
                if (OUTMODE == 1) Cf[(size_t)row * N + col] = v;
                else              Cb[(size_t)row * N + col] = f2bf(v);
            }
        }
    }
}

// ---------------- fused attention: gload_lds pipeline (K/PE mid-chunk, V late) ----------------
// Per chunk: B1(drain) -> QK+PE MFMA -> B2 -> stage K/PE(k+1) [land under softmax+PV]
//            -> softmax -> PV -> B3 -> stage V(k+1) [short drain at next B1].
__global__ __launch_bounds__(256, 2)
void attn_fused7(const u16* __restrict__ Qb, const u16* __restrict__ KVb,
                 const u16* __restrict__ Vtb, const u16* __restrict__ peb,
                 u16* __restrict__ O01, float* __restrict__ lsep,
                 u16* __restrict__ O2) {
    // T1: bid&7 = XCD; each XCD owns 12 consecutive (b,h,sp) groups x 16 qt.
    const int bid = blockIdx.x;
    const int xcd = bid & 7, ii = bid >> 3;
    const int G = xcd * 12 + (ii >> 4), qt = ii & 15;
    const int b = G / 24, rem = G - b * 24;
    const int h = rem / 3, sp = rem - (rem / 3) * 3;

    const int tid = threadIdx.x, w = tid >> 6, lane = tid & 63;
    const int fr = lane & 15, fg = lane >> 4;
    const int q0 = qt * 64, q0w = q0 + w * 16;
    const int n64 = min(2304, q0 + 1344) >> 6;
    const int base = n64 / 3, rm = n64 - base * 3;
    const int cbeg = sp * base + min(sp, rm);
    const int cnt = base + (sp < rm ? 1 : 0);
    const int kbeg = cbeg << 6, kend = (cbeg + cnt) << 6;

    __shared__ __align__(16) u16 Ks[64 * 128];      // row-swizzled
    __shared__ __align__(16) u16 Vs[128 * 64];      // row-swizzled
    __shared__ __align__(16) u16 PEs[2][64 * 128];  // sliding 128-row PE band ring
    __shared__ __align__(16) u16 sc[4][16][84];     // per-wave ppe/p scratch

    const u16* kvbase = KVb + (size_t)b * 2304 * 2048 + h * 128;
    const u16* vtbase = Vtb + (size_t)(b * 8 + h) * 128 * 2304;
    const u16* pebase = peb + (size_t)h * 2304 * 128;
    const float scale2 = 0.088388347648318447f * 1.4426950408889634f;

    bf16x8 qf[4];
    {
        const u16* qp = Qb + (size_t)(b * 1024 + q0w + fr) * 1024 + h * 128 + fg * 8;
        #pragma unroll
        for (int dc = 0; dc < 4; ++dc) qf[dc] = ld8(qp + dc * 32);
    }

    // pre-swizzled global sources (linear LDS dest, inverse-swz source)
    const u16* srcK[4];
    const u16* srcV[4];
    const u16* srcP[4];
    #pragma unroll
    for (int i = 0; i < 4; ++i) {
        const int kr = w * 16 + i * 4 + (lane >> 4);
        srcK[i] = kvbase + (size_t)kr * 2048 + (((lane & 15) ^ (kr & 7)) * 8);
        srcP[i] = pebase + (size_t)kr * 128  + (((lane & 15) ^ (kr & 7)) * 8);
        const int vr = w * 32 + i * 8 + (lane >> 3);
        srcV[i] = vtbase + (size_t)vr * 2304 + (((lane & 7) ^ (vr & 7)) * 8);
    }

    // prologue: stage K, V, PE-lo, PE-hi for chunk kbeg
    {
        const int cc0 = (kbeg - q0) >> 6;
        u16* lo = &PEs[(cc0 + 15) & 1][0];
        u16* up = &PEs[(cc0 + 16) & 1][0];
        const size_t jlo = (size_t)(kbeg - q0 + 960) * 128;
        const size_t jup = (size_t)(kbeg - q0 + 1024) * 128;
        #pragma unroll
        for (int i = 0; i < 4; ++i)
            gload_lds16(srcK[i] + (size_t)kbeg * 2048, Ks + w * 2048 + i * 512);
        #pragma unroll
        for (int i = 0; i < 4; ++i)
            gload_lds16(srcV[i] + kbeg, &Vs[0] + w * 2048 + i * 512);
        #pragma unroll
        for (int i = 0; i < 4; ++i)
            gload_lds16(srcP[i] + jlo, lo + w * 2048 + i * 512);
        #pragma unroll
        for (int i = 0; i < 4; ++i)
            gload_lds16(srcP[i] + jup, up + w * 2048 + i * 512);
    }

    f32x4 o[8] = {};
    float mrow[4] = {-1e30f, -1e30f, -1e30f, -1e30f};
    float lrow[4] = {};

    for (int k0 = kbeg; k0 < kend; k0 += 64) {
        const int cc = (k0 - q0) >> 6;
        const bool more = (k0 + 64 < kend);
        __syncthreads();   // B1: drain staged loads (K/PE issued mid-prev chunk, V at prev end)

        // ---- S = Q K^T + PE band, all LDS-fed ----
        __builtin_amdgcn_s_setprio(1);
        f32x4 s[4] = {};
        #pragma unroll
        for (int kb = 0; kb < 4; ++kb) {
            const int row = kb * 16 + fr;
            #pragma unroll
            for (int dc = 0; dc < 4; ++dc) {
                bf16x8 kf = ld8(Ks + row * 128 + ((dc * 32 + fg * 8) ^ ((row & 7) << 3)));
                s[kb] = mfma16(qf[dc], kf, s[kb]);
            }
        }
        const u16* pl = &PEs[(cc + 15) & 1][0];
        const u16* pu = &PEs[(cc + 16) & 1][0];
        f32x4 pp[5] = {};
        #pragma unroll
        for (int jb = 0; jb < 5; ++jb) {
            const int lstart = 48 - 16 * w + 16 * jb;
            const u16* pbase = (lstart < 64) ? (pl + lstart * 128) : (pu + (lstart - 64) * 128);
            #pragma unroll
            for (int dc = 0; dc < 4; ++dc) {
                bf16x8 pf = ld8(pbase + fr * 128 + ((dc * 32 + fg * 8) ^ ((fr & 7) << 3)));
                pp[jb] = mfma16(qf[dc], pf, pp[jb]);
            }
        }
        __builtin_amdgcn_s_setprio(0);
        #pragma unroll
        for (int jb = 0; jb < 5; ++jb)
            #pragma unroll
            for (int r = 0; r < 4; ++r)
                sc[w][fg * 4 + r][jb * 16 + fr] = f2bf(pp[jb][r]);
        asm volatile("s_waitcnt lgkmcnt(0)" ::: "memory");

        __syncthreads();   // B2: all Ks/PEs reads complete -> safe to restage

        if (more) {
            // stage next chunk's K and PE (lands under softmax+PV)
            #pragma unroll
            for (int i = 0; i < 4; ++i)
                gload_lds16(srcK[i] + (size_t)(k0 + 64) * 2048, Ks + w * 2048 + i * 512);
            u16* pslot = &PEs[(cc + 15) & 1][0];
            const size_t jnext = (size_t)(k0 - q0 + 1088) * 128;
            #pragma unroll
            for (int i = 0; i < 4; ++i)
                gload_lds16(srcP[i] + jnext, pslot + w * 2048 + i * 512);
        }

        // ---- combine + mask + online softmax (exp2 domain) ----
        const bool need_mask = (k0 + 63) > (q0w + 1280);
        float pv[4][4], mx[4];
        #pragma unroll
        for (int r = 0; r < 4; ++r) mx[r] = mrow[r];
        #pragma unroll
        for (int kb = 0; kb < 4; ++kb) {
            #pragma unroll
            for (int r = 0; r < 4; ++r) {
                const int qq = fg * 4 + r;
                float v = (s[kb][r] + bf2f(sc[w][qq][kb * 16 + fr + 15 - qq])) * scale2;
                if (need_mask && (k0 + kb * 16 + fr) > (q0w + qq + 1280)) v = -1e30f;
                pv[kb][r] = v;
                mx[r] = fmaxf(mx[r], v);
            }
        }
        #pragma unroll
        for (int r = 0; r < 4; ++r) {
            mx[r] = fmaxf(mx[r], __shfl_xor(mx[r], 1));
            mx[r] = fmaxf(mx[r], __shfl_xor(mx[r], 2));
            mx[r] = fmaxf(mx[r], __shfl_xor(mx[r], 4));
            mx[r] = fmaxf(mx[r], __shfl_xor(mx[r], 8));
        }
        // T13 defer-rescale
        const float growth = fmaxf(fmaxf(mx[0] - mrow[0], mx[1] - mrow[1]),
                                   fmaxf(mx[2] - mrow[2], mx[3] - mrow[3]));
        if (!__all(growth <= 8.0f)) {
            #pragma unroll
            for (int r = 0; r < 4; ++r) {
                const float a = fexp2(mrow[r] - mx[r]);
                mrow[r] = mx[r];
                lrow[r] *= a;
                #pragma unroll
                for (int db = 0; db < 8; ++db) o[db][r] *= a;
            }
        }
        float rsum[4] = {};
        #pragma unroll
        for (int kb = 0; kb < 4; ++kb)
            #pragma unroll
            for (int r = 0; r < 4; ++r) {
                const float p = fexp2(pv[kb][r] - mrow[r]);
                pv[kb][r] = p;
                rsum[r] += p;
            }
        #pragma unroll
        for (int r = 0; r < 4; ++r) {
            rsum[r] += __shfl_xor(rsum[r], 1);
            rsum[r] += __shfl_xor(rsum[r], 2);
            rsum[r] += __shfl_xor(rsum[r], 4);
            rsum[r] += __shfl_xor(rsum[r], 8);
            lrow[r] += rsum[r];
        }
        // ---- P to scratch (bf16, per-wave region) ----
        #pragma unroll
        for (int kb = 0; kb < 4; ++kb)
            #pragma unroll
            for (int r = 0; r < 4; ++r)
                sc[w][fg * 4 + r][kb * 16 + fr] = f2bf(pv[kb][r]);
        asm volatile("s_waitcnt lgkmcnt(0)" ::: "memory");
        // ---- O += P V (V from LDS) ----
        __builtin_amdgcn_s_setprio(1);
        #pragma unroll
        for (int ks = 0; ks < 2; ++ks) {
            bf16x8 pa = __builtin_bit_cast(bf16x8, *(const uint4*)(&sc[w][fr][ks * 32 + fg * 8]));
            #pragma unroll
            for (int db = 0; db < 8; ++db) {
                const int d = db * 16 + fr;
                bf16x8 vf = ld8(Vs + d * 64 + ((ks * 32 + fg * 8) ^ ((d & 7) << 3)));
                o[db] = mfma16(pa, vf, o[db]);
            }
        }
        __builtin_amdgcn_s_setprio(0);

        __syncthreads();   // B3: all Vs reads complete (K/PE stage long landed)

        if (more) {
            // stage next chunk's V; drained at next B1 (short, L2-local)
            #pragma unroll
            for (int i = 0; i < 4; ++i)
                gload_lds16(srcV[i] + (k0 + 64), &Vs[0] + w * 2048 + i * 512);
        }
    }
    // ---- epilogue: normalized partial + lse (log2 domain) ----
    float inv[4], lse[4];
    #pragma unroll
    for (int r = 0; r < 4; ++r) {
        inv[r] = 1.0f / lrow[r];
        lse[r] = mrow[r] + flog2(lrow[r]);
    }
    u16* dst = (sp == 2) ? O2 : (O01 + (size_t)sp * 4194304);
    #pragma unroll
    for (int db = 0; db < 8; ++db)
        #pragma unroll
        for (int r = 0; r < 4; ++r)
            dst[(size_t)(b * 1024 + q0w + fg * 4 + r) * 1024 + h * 128 + db * 16 + fr]
                = f2bf(o[db][r] * inv[r]);
    if (fr == 0) {
        #pragma unroll
        for (int r = 0; r < 4; ++r)
            lsep[sp * 32768 + (b * 8 + h) * 1024 + q0w + fg * 4 + r] = lse[r];
    }
}

// combine 3 flash partials (lse in log2 domain)
__global__ void attn_combine(const u16* __restrict__ O01, const float* __restrict__ lsep,
                             u16* __restrict__ O2) {
    const int i = (blockIdx.x * 256 + threadIdx.x) * 8;
    const int row = i >> 10;
    const int b = row >> 10, q = row & 1023;
    const int h = (i & 1023) >> 7;
    const int li = (b * 8 + h) * 1024 + q;
    const float l0 = lsep[li], l1 = lsep[li + 32768], l2 = lsep[li + 65536];
    const float M = fmaxf(l0, fmaxf(l1, l2));
    const float w0 = fexp2(l0 - M), w1 = fexp2(l1 - M), w2 = fexp2(l2 - M);
    const float inv = 1.0f / (w0 + w1 + w2);
    uint4 a = *(const uint4*)(O01 + i);
    uint4 c = *(const uint4*)(O01 + 4194304 + i);
    uint4 e = *(const uint4*)(O2 + i);
    const u16* ap = (const u16*)&a;
    const u16* cp = (const u16*)&c;
    const u16* ep = (const u16*)&e;
    u16 ov[8];
    #pragma unroll
    for (int j = 0; j < 8; ++j)
        ov[j] = f2bf((w0 * bf2f(ap[j]) + w1 * bf2f(cp[j]) + w2 * bf2f(ep[j])) * inv);
    *(uint4*)(O2 + i) = *(const uint4*)ov;
}

// ---------------- launch ----------------

extern "C" void kernel_launch(void* const* d_in, const int* in_sizes, int n_in,
                              void* d_out, int out_size, void* d_ws, size_t ws_size,
                              hipStream_t stream) {
    const float* x     = (const float*)d_in[0];
    const float* mem   = (const float*)d_in[1];
    const float* cmem  = (const float*)d_in[2];
    const float* pos   = (const float*)d_in[3];
    const float* Wq    = (const float*)d_in[5];
    const float* Wkv   = (const float*)d_in[6];
    const float* Wout  = (const float*)d_in[7];
    const float* bout  = (const float*)d_in[8];
    const float* convw = (const float*)d_in[9];
    const float* convb = (const float*)d_in[10];
    float* out = (float*)d_out;

    u16* ws = (u16*)d_ws;
    size_t off = 0;
    u16* kvin   = ws + off; off += (size_t)9216 * 1024;   // also reused as O-partials
    u16* WqT    = ws + off; off += (size_t)1024 * 1024;
    u16* WkvT   = ws + off; off += (size_t)2048 * 1024;
    u16* WoutT  = ws + off; off += (size_t)1024 * 1024;
    u16* convWT = ws + off; off += (size_t)1024 * 4096;
    u16* peb    = ws + off; off += (size_t)8 * 2304 * 128;
    u16* Qb     = ws + off; off += (size_t)4096 * 1024;
    u16* KVb    = ws + off; off += (size_t)9216 * 2048;
    u16* Vtb    = ws + off; off += (size_t)4 * 8 * 128 * 2304;
    u16* attn   = ws + off; off += (size_t)4096 * 1024;

    u16* O01 = kvin;                             // splits 0,1: 2 x 4194304 u16
    float* lsep = (float*)(kvin + 8388608);      // 3 x 32768 f32

    prep_all<<<16640, 256, 0, stream>>>(x, mem, cmem, pos, Wq, Wkv, Wout, convw,
                                        kvin, peb, WqT, WkvT, WoutT, convWT);

    // Q = x @ Wq  (rows remapped into kvin)
    gemm_bt<2, 128, 128><<<dim3(8, 32), 256, 0, stream>>>(
        kvin, WqT, nullptr, Qb, nullptr, 1024, 1024, 1024, 2304, 1280, nullptr);
    // KV = kv_input @ Wkv ; V-half written transposed (via LDS) into Vtb
    gemm_bt<4, 128, 128><<<dim3(16, 72), 256, 0, stream>>>(
        kvin, WkvT, nullptr, KVb, nullptr, 2048, 1024, 9216, 0, 0, Vtb);

    // new_cmem (conv) BEFORE attention clobbers kvin
    gemm_bt<1, 64, 64><<<dim3(16, 16), 256, 0, stream>>>(
        kvin, convWT, out + 8388608, nullptr, convb, 1024, 4096, 256, 576, 64, nullptr);
    // new_mem = x
    hipMemcpyAsync(out + 4194304, x, (size_t)4 * 1024 * 1024 * 4,
                   hipMemcpyDeviceToDevice, stream);

    attn_fused7<<<dim3(1536), 256, 0, stream>>>(Qb, KVb, Vtb, peb, O01, lsep, attn);
    attn_combine<<<2048, 256, 0, stream>>>(O01, lsep, attn);

    // logits = attn_out @ Wout + b_out
    gemm_bt<1, 128, 128><<<dim3(8, 32), 256, 0, stream>>>(
        attn, WoutT, out, nullptr, bout, 1024, 1024, 4096, 0, 0, nullptr);
    // aux_loss = 0
    hipMemsetAsync(out + 9437184, 0, 4, stream);
}